// Round 10
// baseline (173.933 us; speedup 1.0000x reference)
//
#include <hip/hip_runtime.h>
#include <math.h>

#define QSCALE (0.2886751345948129f * 1.4426950408889634f)  // 1/sqrt(12) * log2(e)

#if __has_builtin(__builtin_amdgcn_exp2f)
#define EXP2F(x) __builtin_amdgcn_exp2f(x)
#else
#define EXP2F(x) exp2f(x)
#endif

typedef __attribute__((ext_vector_type(8))) _Float16 half8;
typedef __attribute__((ext_vector_type(4))) _Float16 half4_t;
typedef __attribute__((ext_vector_type(4))) float floatx4;

#define MFMA32F16(a, b, c) __builtin_amdgcn_mfma_f32_16x16x32_f16((a), (b), (c), 0, 0, 0)
#define MFMA16F16(a, b, c) __builtin_amdgcn_mfma_f32_16x16x16f16((a), (b), (c), 0, 0, 0)

static __device__ inline float bperm(float v, int addr_bytes) {
    return __int_as_float(__builtin_amdgcn_ds_bpermute(addr_bytes, __float_as_int(v)));
}

// ---------------- Kernel P: weight swizzle -> fp16 hi/lo B-frags -----------
__global__ __launch_bounds__(256)
void prep(const float* __restrict__ Wq, const float* __restrict__ Wk,
          const float* __restrict__ Wv, _Float16* __restrict__ wfh,
          _Float16* __restrict__ wfl)
{
    int t = blockIdx.x * 256 + threadIdx.x;
    if (t >= 4608) return;                 // 24 ks * 3 nt * 64 lanes
    int lane = t & 63;
    int nt   = (t >> 6) % 3;
    int ks   = t / 192;
    const float* W = (nt == 0) ? Wq : (nt == 1) ? Wk : Wv;
    const float scale = (nt == 0) ? QSCALE : 1.0f;
    int col = lane & 15;
    int kq  = lane >> 4;
    half8 hi, lo;
    #pragma unroll
    for (int j = 0; j < 8; ++j) {
        int dim = ks * 32 + kq * 8 + j;
        float f = (col < 12) ? W[dim * 12 + col] * scale : 0.0f;
        _Float16 h = (_Float16)f;
        hi[j] = h;
        lo[j] = (_Float16)(f - (float)h);
    }
    size_t off = ((size_t)(ks * 3 + nt) * 64 + lane) * 8;
    *(half8*)(wfh + off) = hi;
    *(half8*)(wfl + off) = lo;
}

// ---------------- Kernel 1: QKV projection, fp16-split MFMA ----------------
// grid=1024, block=256, XCD-aligned remap (producer batch == consumer XCD).
// Main loop identical to round 9. Epilogue now emits PACKED attention frags:
//   kpk = [kh | kl]  (kh in k-slots 0..11, kl in 16..27)  -- one 16B load
//   qp1 = [qh | qh], qp2 = [ql | 0]
// so attn does 2 QK MFMAs/tile instead of 3 and loads 24B not 40B.
__global__ __launch_bounds__(256, 3)
void qkv_mfma(const float* __restrict__ x, const _Float16* __restrict__ wfh,
              const _Float16* __restrict__ wfl, const int* __restrict__ mask,
              _Float16* __restrict__ qp1f, _Float16* __restrict__ qp2f,
              _Float16* __restrict__ kpkf, _Float16* __restrict__ vtf)
{
    __shared__ __align__(16) float smem[3072];   // 12 KB: cbuf, then frag tiles
    const int tid  = threadIdx.x;
    const int lane = tid & 63;
    const int w    = tid >> 6;
    const int g    = ((blockIdx.x & 7) << 7) | (blockIdx.x >> 3);  // XCD-aligned
    const int rowbase = g * 16;
    const int m15 = lane & 15;
    const int q8  = lane >> 4;

    const float* xbase = x + (size_t)(rowbase + m15) * 768 + q8 * 8;
    const half8* WH = (const half8*)wfh;
    const half8* WL = (const half8*)wfl;

    // issue ALL x loads up front (independent, 12 in flight)
    float xv[6][8];
    #pragma unroll
    for (int s = 0; s < 6; ++s) {
        const int ks = w * 6 + s;
        *(float4*)(xv[s])     = *(const float4*)(xbase + ks * 32);
        *(float4*)(xv[s] + 4) = *(const float4*)(xbase + ks * 32 + 4);
    }

    floatx4 acc0 = {0.f, 0.f, 0.f, 0.f};
    floatx4 acc1 = acc0, acc2 = acc0;

    half8 bh[2][3], bl[2][3];
    {
        const int ks = w * 6;
        #pragma unroll
        for (int n = 0; n < 3; ++n) {
            bh[0][n] = WH[(ks * 3 + n) * 64 + lane];
            bl[0][n] = WL[(ks * 3 + n) * 64 + lane];
        }
    }

    #pragma unroll
    for (int s = 0; s < 6; ++s) {
        const int cur = s & 1, nxt = cur ^ 1;
        if (s < 5) {
            const int ksn = w * 6 + s + 1;
            #pragma unroll
            for (int n = 0; n < 3; ++n) {
                bh[nxt][n] = WH[(ksn * 3 + n) * 64 + lane];
                bl[nxt][n] = WL[(ksn * 3 + n) * 64 + lane];
            }
        }
        half8 ah, al;
        #pragma unroll
        for (int j = 0; j < 8; ++j) {
            _Float16 h = (_Float16)xv[s][j];
            ah[j] = h;
            al[j] = (_Float16)(xv[s][j] - (float)h);
        }
        acc0 = MFMA32F16(ah, bh[cur][0], acc0);
        acc1 = MFMA32F16(ah, bh[cur][1], acc1);
        acc2 = MFMA32F16(ah, bh[cur][2], acc2);
        acc0 = MFMA32F16(al, bh[cur][0], acc0);
        acc1 = MFMA32F16(al, bh[cur][1], acc1);
        acc2 = MFMA32F16(al, bh[cur][2], acc2);
        acc0 = MFMA32F16(ah, bl[cur][0], acc0);
        acc1 = MFMA32F16(ah, bl[cur][1], acc1);
        acc2 = MFMA32F16(ah, bl[cur][2], acc2);
    }

    // ---- cross-wave combine ----
    *(floatx4*)(smem + ((w * 3 + 0) * 64 + lane) * 4) = acc0;
    *(floatx4*)(smem + ((w * 3 + 1) * 64 + lane) * 4) = acc1;
    *(floatx4*)(smem + ((w * 3 + 2) * 64 + lane) * 4) = acc2;
    __syncthreads();
    floatx4 tot = {0.f, 0.f, 0.f, 0.f};
    if (w < 3) {
        floatx4 t0 = *(const floatx4*)(smem + ((0 * 3 + w) * 64 + lane) * 4);
        floatx4 t1 = *(const floatx4*)(smem + ((1 * 3 + w) * 64 + lane) * 4);
        floatx4 t2 = *(const floatx4*)(smem + ((2 * 3 + w) * 64 + lane) * 4);
        floatx4 t3 = *(const floatx4*)(smem + ((3 * 3 + w) * 64 + lane) * 4);
        tot = t0 + t1 + t2 + t3;
    }
    __syncthreads();   // all cbuf reads done; reuse smem as fragment tiles

    // frag tiles (halves): qp1[0,512) qp2[512,1024) kpk[1024,1536) vt[1536,1792)
    _Float16* sh = (_Float16*)smem;
    {   // zero-init 1792 halves = 896 dwords
        unsigned* zp = (unsigned*)smem;
        for (int i = tid; i < 896; i += 256) zp[i] = 0u;
    }
    __syncthreads();

    if (w < 3) {
        const int col = m15;
        const int r0  = q8 * 4;
        int msk[4];
        #pragma unroll
        for (int r = 0; r < 4; ++r) msk[r] = mask[rowbase + r0 + r];
        #pragma unroll
        for (int r = 0; r < 4; ++r) {
            const int row = r0 + r;            // row / key slot within tile
            const float val = tot[r];
            if (w == 0) {                      // Q: qp1=[qh|qh], qp2=[ql|0]
                if (col < 12) {
                    int idx = ((col >> 3) * 16 + row) * 8 + (col & 7);
                    int idx2 = (((col >> 3) + 2) * 16 + row) * 8 + (col & 7);
                    _Float16 h = (_Float16)val;
                    sh[idx]        = h;
                    sh[idx2]       = h;
                    sh[512 + idx]  = (_Float16)(val - (float)h);
                }
            } else if (w == 1) {               // K: kpk=[kh|kl], zero-masked
                if (col < 12 && msk[r]) {
                    int idx  = ((col >> 3) * 16 + row) * 8 + (col & 7);
                    int idx2 = (((col >> 3) + 2) * 16 + row) * 8 + (col & 7);
                    _Float16 h = (_Float16)val;
                    sh[1024 + idx]  = h;
                    sh[1024 + idx2] = (_Float16)(val - (float)h);
                }
            } else {                           // V^T tile + ones row (l)
                if (col < 12) {
                    if (msk[r]) {
                        int idx = ((row >> 2) * 16 + col) * 4 + (row & 3);
                        sh[1536 + idx] = (_Float16)val;
                    }
                } else if (col == 12) {
                    int idx = ((row >> 2) * 16 + 12) * 4 + (row & 3);
                    sh[1536 + idx] = (_Float16)(msk[r] ? 1.f : 0.f);
                }
            }
        }
    }
    __syncthreads();

    // coalesced tile stores: 64 lanes x 16B (or 8B) each
    const int bb = g >> 7;
    const int tt = g & 127;
    const size_t tb64 = (size_t)(bb * 128 + tt) * 64;
    if (w == 0) {
        ((half8*)qp1f)[(size_t)g * 64 + lane] = ((const half8*)(sh))[lane];
        ((half8*)qp2f)[(size_t)g * 64 + lane] = ((const half8*)(sh + 512))[lane];
    } else if (w == 1) {
        ((half8*)kpkf)[tb64 + lane] = ((const half8*)(sh + 1024))[lane];
    } else if (w == 2) {
        ((half4_t*)vtf)[tb64 + lane] = ((const half4_t*)(sh + 1536))[lane];
    }
}

// ---------------- Kernel 2: MFMA flash attention (packed K) ----------------
// grid=256 (4 q-groups/block), block=512 (8 waves stride-8 over 128 tiles).
// Per tile per group: 2 QK MFMAs (packed [kh|kl] vs [qh|qh],[ql|0]) + 1 PV.
// 24 B/lane-tile loads (kpk 16 + vt 8), 2-deep prefetch. XCD-pinned batches.
__global__ __launch_bounds__(512)
void attn(const _Float16* __restrict__ qp1f, const _Float16* __restrict__ qp2f,
          const _Float16* __restrict__ kpkf, const _Float16* __restrict__ vtf,
          float* __restrict__ out)
{
    __shared__ float cm[2048];                    // [gi*8+w][lane]
    __shared__ __align__(16) floatx4 co[2048];    // [gi*8+w][lane]
    const int tid  = threadIdx.x;
    const int lane = tid & 63;
    const int w    = tid >> 6;             // 0..7
    const int bb   = blockIdx.x & 7;       // XCD-pinned batch
    const int gl   = blockIdx.x >> 3;      // 0..31 within batch
    const int g0   = bb * 128 + gl * 4;    // first of 4 q-groups
    const int m15  = lane & 15;

    half8 qp1[4], qp2[4];
    #pragma unroll
    for (int gi = 0; gi < 4; ++gi) {
        qp1[gi] = *(const half8*)(qp1f + ((size_t)(g0 + gi) * 64 + lane) * 8);
        qp2[gi] = *(const half8*)(qp2f + ((size_t)(g0 + gi) * 64 + lane) * 8);
    }

    const half8* KP = (const half8*)kpkf + (size_t)bb * 128 * 64;
    const half4_t* VT = (const half4_t*)vtf + (size_t)bb * 128 * 64;

    const int a16 = (lane ^ 16) << 2;
    const int a32 = (lane ^ 32) << 2;
    const int a48 = (lane ^ 48) << 2;

    float m[4] = {-INFINITY, -INFINITY, -INFINITY, -INFINITY};
    floatx4 o[4];
    #pragma unroll
    for (int gi = 0; gi < 4; ++gi) o[gi] = (floatx4){0.f, 0.f, 0.f, 0.f};

    // 2-deep prefetch pipeline
    half8 kp[2];  half4_t va[2];
    kp[0] = KP[w * 64 + lane];
    va[0] = VT[w * 64 + lane];
    kp[1] = KP[(w + 8) * 64 + lane];
    va[1] = VT[(w + 8) * 64 + lane];

    for (int it = 0; it < 16; ++it) {
        const int cur = it & 1;
        half8 ck = kp[cur];
        half4_t cv = va[cur];
        const int tn = w + (it + 2) * 8;
        if (tn < 128) {
            kp[cur] = KP[tn * 64 + lane];
            va[cur] = VT[tn * 64 + lane];
        }
        floatx4 s[4];
        #pragma unroll
        for (int gi = 0; gi < 4; ++gi) s[gi] = (floatx4){0.f, 0.f, 0.f, 0.f};
        #pragma unroll
        for (int gi = 0; gi < 4; ++gi) s[gi] = MFMA32F16(ck, qp1[gi], s[gi]);
        #pragma unroll
        for (int gi = 0; gi < 4; ++gi) s[gi] = MFMA32F16(ck, qp2[gi], s[gi]);
        #pragma unroll
        for (int gi = 0; gi < 4; ++gi) {
            float pm = fmaxf(fmaxf(s[gi].x, s[gi].y), fmaxf(s[gi].z, s[gi].w));
            float b1 = bperm(pm, a16);
            float b2 = bperm(pm, a32);
            float b3 = bperm(pm, a48);
            pm = fmaxf(fmaxf(pm, b1), fmaxf(b2, b3));
            float mnew = fmaxf(m[gi], pm);
            float corr = EXP2F(m[gi] - mnew);
            o[gi].x *= corr; o[gi].y *= corr; o[gi].z *= corr; o[gi].w *= corr;
            half4_t pb;
            pb[0] = (_Float16)EXP2F(s[gi].x - mnew);
            pb[1] = (_Float16)EXP2F(s[gi].y - mnew);
            pb[2] = (_Float16)EXP2F(s[gi].z - mnew);
            pb[3] = (_Float16)EXP2F(s[gi].w - mnew);
            o[gi] = MFMA16F16(cv, pb, o[gi]);
            m[gi] = mnew;
        }
    }

    #pragma unroll
    for (int gi = 0; gi < 4; ++gi) {
        cm[(gi * 8 + w) * 64 + lane] = m[gi];
        co[(gi * 8 + w) * 64 + lane] = o[gi];
    }
    __syncthreads();
    if (w < 4) {
        const int gi = w;
        float gm = -INFINITY;
        #pragma unroll
        for (int w2 = 0; w2 < 8; ++w2) gm = fmaxf(gm, cm[(gi * 8 + w2) * 64 + lane]);
        floatx4 O = {0.f, 0.f, 0.f, 0.f};
        #pragma unroll
        for (int w2 = 0; w2 < 8; ++w2) {
            float f = EXP2F(cm[(gi * 8 + w2) * 64 + lane] - gm);
            floatx4 ow = co[(gi * 8 + w2) * 64 + lane];
            O.x += ow.x * f; O.y += ow.y * f; O.z += ow.z * f; O.w += ow.w * f;
        }
        float L = bperm(O.x, (48 + m15) << 2);   // l at C row 12
        float inv = 1.0f / L;
        if ((lane >> 4) < 3) {
            float4 ov = make_float4(O.x * inv, O.y * inv, O.z * inv, O.w * inv);
            *(float4*)(out + ((size_t)(g0 + gi) * 16 + m15) * 12 + (lane >> 4) * 4) = ov;
        }
    }
}

extern "C" void kernel_launch(void* const* d_in, const int* in_sizes, int n_in,
                              void* d_out, int out_size, void* d_ws, size_t ws_size,
                              hipStream_t stream) {
    const float* x    = (const float*)d_in[0];
    const int*   mask = (const int*)  d_in[1];
    const float* Wk   = (const float*)d_in[2];   // key_weight
    const float* Wq   = (const float*)d_in[3];   // query_weight
    const float* Wv   = (const float*)d_in[4];   // value_weight
    float* out = (float*)d_out;

    char* base = (char*)d_ws;
    _Float16* qp1f = (_Float16*)(base);                    // 1 MB
    _Float16* qp2f = (_Float16*)(base + (1u << 20));       // 1 MB
    _Float16* kpkf = (_Float16*)(base + (2u << 20));       // 1 MB
    _Float16* vtf  = (_Float16*)(base + (3u << 20));       // 0.5 MB
    _Float16* wfh  = (_Float16*)(base + 3670016);          // 73728 B
    _Float16* wfl  = (_Float16*)(base + 3670016 + 73728);  // 73728 B

    prep<<<18, 256, 0, stream>>>(Wq, Wk, Wv, wfh, wfl);
    qkv_mfma<<<1024, 256, 0, stream>>>(x, wfh, wfl, mask, qp1f, qp2f, kpkf, vtf);
    attn<<<256, 512, 0, stream>>>(qp1f, qp2f, kpkf, vtf, out);
}